// Round 2
// baseline (171.264 us; speedup 1.0000x reference)
//
#include <hip/hip_runtime.h>

// EntityLinker forward, MI355X/gfx950.
// One block per batch element b (grid=1024, 256 threads = 4 waves).
// Phases: gather -> q_summary -> sim MFMA + in-reg softmax -> wq MFMA ->
//         feats pieces (bf16, LDS) -> K=640 GEMM vs W_h^T (bf16, ws) -> out.

typedef __attribute__((ext_vector_type(8))) short     short8;
typedef __attribute__((ext_vector_type(8))) __bf16    bf16x8;
typedef __attribute__((ext_vector_type(4))) float     f32x4;

#define SWZ(row, off) ((off) ^ (((row) & 7) << 4))

// ---- LDS layout (bytes). Aliases: QH->wq piece, QHT->absd piece. ----
#define CH_OFF    0        // c_h   [64][128] bf16, 256B rows, swizzled
#define QH_OFF    16384    // q_h   [64][128] bf16  (later: wq piece)
#define QHT_OFF   32768    // q_hT  [128][64] bf16, 128B rows (later: absd piece [64][128])
#define ATT_OFF   49152    // att   [64][64]  bf16, 128B rows
#define PROD_OFF  57344    // prod  [64][128] bf16
#define QPART_OFF 73728    // qpart [8][128] f32
#define QSUM_OFF  77824    // qsum  [128] bf16
#define OUTP_OFF  78080    // out_part [4][64] f32
#define LDS_SIZE  79104

__device__ __forceinline__ unsigned short f2bf(float x) {
    unsigned u = __builtin_bit_cast(unsigned, x);
    u += 0x7FFFu + ((u >> 16) & 1u);          // RNE
    return (unsigned short)(u >> 16);
}
__device__ __forceinline__ float bf2f(unsigned short u) {
    return __builtin_bit_cast(float, ((unsigned)u) << 16);
}
__device__ __forceinline__ f32x4 mfma16(short8 a, short8 b, f32x4 c) {
    return __builtin_amdgcn_mfma_f32_16x16x32_bf16(
        __builtin_bit_cast(bf16x8, a), __builtin_bit_cast(bf16x8, b), c, 0, 0, 0);
}

// Prep: W_h [640][128] f32 row-major -> W_h^T [128][640] bf16 in workspace.
__global__ __launch_bounds__(256) void el_prep(const float* __restrict__ W_h,
                                               unsigned short* __restrict__ whT) {
    int t = blockIdx.x * 256 + threadIdx.x;   // 0..81919
    int k = t >> 7, n = t & 127;
    whT[n * 640 + k] = f2bf(W_h[t]);          // W_h[t] == W_h[k*128 + n]
}

__global__ __launch_bounds__(256) void el_main(
    const int* __restrict__ q_ids, const int* __restrict__ c_ids,
    const int* __restrict__ num_qs, const float* __restrict__ embed,
    const unsigned short* __restrict__ whT, const float* __restrict__ b_h,
    const float* __restrict__ W_o, const float* __restrict__ b_o,
    float* __restrict__ out)
{
    __shared__ __align__(16) char smem[LDS_SIZE];
    const int tid = threadIdx.x;
    const int b = blockIdx.x;
    const int nq = num_qs[b];

    // ---------------- P1: gathers ----------------
    {
        const int l = tid & 31, g = tid >> 5;            // 8 groups of 32 lanes
        // c_h: masked mean over 8 tokens; group g handles cols g, g+8, ...
        for (int c = g; c < 64; c += 8) {
            const int* cid = c_ids + ((b << 6) + c) * 8;
            f32x4 acc = {0.f, 0.f, 0.f, 0.f};
            int cnt = 0;
            #pragma unroll
            for (int t = 0; t < 8; ++t) {
                int id = cid[t];
                cnt += (id != 0);
                f32x4 v = *(const f32x4*)(embed + (long)id * 128 + l * 4); // row0 == 0
                acc += v;
            }
            float inv = 1.0f / (float)(cnt > 0 ? cnt : 1);
            unsigned u01 = (unsigned)f2bf(acc[0] * inv) | ((unsigned)f2bf(acc[1] * inv) << 16);
            unsigned u23 = (unsigned)f2bf(acc[2] * inv) | ((unsigned)f2bf(acc[3] * inv) << 16);
            uint2 pk; pk.x = u01; pk.y = u23;
            *(uint2*)(smem + CH_OFF + SWZ(c, c * 256 + l * 8)) = pk;
        }
        // q_h + q_hT + per-group q_summary partials
        f32x4 qacc = {0.f, 0.f, 0.f, 0.f};
        for (int q = g; q < 64; q += 8) {
            int id = q_ids[(b << 6) + q];
            f32x4 v = *(const f32x4*)(embed + (long)id * 128 + l * 4);
            unsigned u01 = (unsigned)f2bf(v[0]) | ((unsigned)f2bf(v[1]) << 16);
            unsigned u23 = (unsigned)f2bf(v[2]) | ((unsigned)f2bf(v[3]) << 16);
            uint2 pk; pk.x = u01; pk.y = u23;
            *(uint2*)(smem + QH_OFF + SWZ(q, q * 256 + l * 8)) = pk;
            #pragma unroll
            for (int i = 0; i < 4; ++i) {               // transpose writes (conflicted, small)
                int d = l * 4 + i;
                *(unsigned short*)(smem + QHT_OFF + SWZ(d, d * 128 + q * 2)) = f2bf(v[i]);
            }
            if (q < nq) qacc += v;
        }
        *(f32x4*)(smem + QPART_OFF + (g * 128 + l * 4) * 4) = qacc;
    }
    __syncthreads();

    // ---------------- P2: q_summary (bf16) ----------------
    if (tid < 128) {
        float s = 0.f;
        #pragma unroll
        for (int g = 0; g < 8; ++g)
            s += *(const float*)(smem + QPART_OFF + (g * 128 + tid) * 4);
        s /= (float)(nq > 0 ? nq : 1);
        *(unsigned short*)(smem + QSUM_OFF + tid * 2) = f2bf(s);
    }
    __syncthreads();

    const int lane = tid & 63, w = tid >> 6;
    const int lr = lane & 15, lg = lane >> 4;

    // ---------------- P3: sim = c_h q_h^T /sqrt(D), softmax, att ----------------
    {
        short8 a[4];
        const int arow = w * 16 + lr;
        #pragma unroll
        for (int s = 0; s < 4; ++s)
            a[s] = *(const short8*)(smem + CH_OFF + SWZ(arow, arow * 256 + s * 64 + lg * 16));
        f32x4 sim[4];
        #pragma unroll
        for (int ct = 0; ct < 4; ++ct) {
            f32x4 acc = {0.f, 0.f, 0.f, 0.f};
            const int q = ct * 16 + lr;
            #pragma unroll
            for (int s = 0; s < 4; ++s) {
                short8 bf = *(const short8*)(smem + QH_OFF + SWZ(q, q * 256 + s * 64 + lg * 16));
                acc = mfma16(a[s], bf, acc);
            }
            sim[ct] = acc;
        }
        const float scale = 0.08838834764831845f;  // 1/sqrt(128)
        #pragma unroll
        for (int ct = 0; ct < 4; ++ct) {
            const int q = ct * 16 + lr;
            #pragma unroll
            for (int r = 0; r < 4; ++r)
                sim[ct][r] = (q < nq) ? sim[ct][r] * scale : -3.0e38f;
        }
        float mx[4], sm[4];
        #pragma unroll
        for (int r = 0; r < 4; ++r)
            mx[r] = fmaxf(fmaxf(sim[0][r], sim[1][r]), fmaxf(sim[2][r], sim[3][r]));
        #pragma unroll
        for (int off = 1; off <= 8; off <<= 1)
            #pragma unroll
            for (int r = 0; r < 4; ++r)
                mx[r] = fmaxf(mx[r], __shfl_xor(mx[r], off));
        #pragma unroll
        for (int ct = 0; ct < 4; ++ct)
            #pragma unroll
            for (int r = 0; r < 4; ++r)
                sim[ct][r] = __expf(sim[ct][r] - mx[r]);
        #pragma unroll
        for (int r = 0; r < 4; ++r)
            sm[r] = (sim[0][r] + sim[1][r]) + (sim[2][r] + sim[3][r]);
        #pragma unroll
        for (int off = 1; off <= 8; off <<= 1)
            #pragma unroll
            for (int r = 0; r < 4; ++r)
                sm[r] += __shfl_xor(sm[r], off);
        float inv[4];
        #pragma unroll
        for (int r = 0; r < 4; ++r) inv[r] = 1.0f / sm[r];
        const int cbase = w * 16 + lg * 4;
        #pragma unroll
        for (int ct = 0; ct < 4; ++ct)
            #pragma unroll
            for (int r = 0; r < 4; ++r) {
                int c = cbase + r, q = ct * 16 + lr;
                *(unsigned short*)(smem + ATT_OFF + SWZ(c, c * 128 + q * 2)) =
                    f2bf(sim[ct][r] * inv[r]);
            }
    }
    __syncthreads();

    // ---------------- P4: weighted_q = att @ q_h ----------------
    f32x4 wqa[8];
    {
        short8 pa[2];
        const int prow = w * 16 + lr;
        #pragma unroll
        for (int s = 0; s < 2; ++s)
            pa[s] = *(const short8*)(smem + ATT_OFF + SWZ(prow, prow * 128 + s * 64 + lg * 16));
        #pragma unroll
        for (int ct = 0; ct < 8; ++ct) {
            f32x4 acc = {0.f, 0.f, 0.f, 0.f};
            const int dcol = ct * 16 + lr;
            #pragma unroll
            for (int s = 0; s < 2; ++s) {
                short8 bf = *(const short8*)(smem + QHT_OFF + SWZ(dcol, dcol * 128 + s * 64 + lg * 16));
                acc = mfma16(pa[s], bf, acc);
            }
            wqa[ct] = acc;
        }
    }
    __syncthreads();   // all q_hT reads done before absd overwrites that region
    {
        const int cbase = w * 16 + lg * 4;
        #pragma unroll
        for (int ct = 0; ct < 8; ++ct)
            #pragma unroll
            for (int r = 0; r < 4; ++r) {
                int c = cbase + r, d = ct * 16 + lr;
                int off = c * 256 + d * 2;
                float wqv = wqa[ct][r];
                float chv = bf2f(*(const unsigned short*)(smem + CH_OFF + SWZ(c, off)));
                *(unsigned short*)(smem + QH_OFF  + SWZ(c, off)) = f2bf(wqv);
                *(unsigned short*)(smem + PROD_OFF + SWZ(c, off)) = f2bf(chv * wqv);
                *(unsigned short*)(smem + QHT_OFF + SWZ(c, off)) = f2bf(fabsf(chv - wqv));
            }
    }
    __syncthreads();

    // ---------------- P5: h = tanh(feats @ W_h + b_h); out = h @ W_o ----------------
    {
        f32x4 acc[4][2];
        #pragma unroll
        for (int rt = 0; rt < 4; ++rt)
            #pragma unroll
            for (int j = 0; j < 2; ++j)
                acc[rt][j] = (f32x4){0.f, 0.f, 0.f, 0.f};

        const int n0 = (w * 2) * 16 + lr;
        const int n1 = (w * 2 + 1) * 16 + lr;
        const int klane = lg * 8;
        short8 b0 = *(const short8*)(whT + n0 * 640 + klane);
        short8 b1 = *(const short8*)(whT + n1 * 640 + klane);

        for (int s = 0; s < 20; ++s) {
            short8 nb0 = b0, nb1 = b1;
            if (s < 19) {
                nb0 = *(const short8*)(whT + n0 * 640 + (s + 1) * 32 + klane);
                nb1 = *(const short8*)(whT + n1 * 640 + (s + 1) * 32 + klane);
            }
            const int p = s >> 2, sk = (s & 3) * 32;
            if (p == 0) {  // q_summary broadcast rows
                short8 afr = *(const short8*)(smem + QSUM_OFF + sk * 2 + lg * 16);
                #pragma unroll
                for (int rt = 0; rt < 4; ++rt) {
                    acc[rt][0] = mfma16(afr, b0, acc[rt][0]);
                    acc[rt][1] = mfma16(afr, b1, acc[rt][1]);
                }
            } else {
                const int base = (p == 1) ? CH_OFF : (p == 2) ? QH_OFF
                               : (p == 3) ? PROD_OFF : QHT_OFF;
                #pragma unroll
                for (int rt = 0; rt < 4; ++rt) {
                    int row = rt * 16 + lr;
                    short8 afr = *(const short8*)(smem + base + SWZ(row, row * 256 + sk * 2 + lg * 16));
                    acc[rt][0] = mfma16(afr, b0, acc[rt][0]);
                    acc[rt][1] = mfma16(afr, b1, acc[rt][1]);
                }
            }
            b0 = nb0; b1 = nb1;
        }

        float bh0 = b_h[n0], bh1 = b_h[n1];
        float wo0 = W_o[n0], wo1 = W_o[n1];
        #pragma unroll
        for (int rt = 0; rt < 4; ++rt)
            #pragma unroll
            for (int r = 0; r < 4; ++r) {
                float x0 = acc[rt][0][r] + bh0;
                float x1 = acc[rt][1][r] + bh1;
                float t0 = 1.0f - 2.0f / (__expf(2.0f * x0) + 1.0f);  // tanh
                float t1 = 1.0f - 2.0f / (__expf(2.0f * x1) + 1.0f);
                float po = t0 * wo0 + t1 * wo1;
                #pragma unroll
                for (int off = 1; off <= 8; off <<= 1)
                    po += __shfl_xor(po, off);
                if (lr == 0)
                    *(float*)(smem + OUTP_OFF + (w * 64 + rt * 16 + lg * 4 + r) * 4) = po;
            }
    }
    __syncthreads();

    // ---------------- P6: combine wave partials ----------------
    if (tid < 64) {
        float o = b_o[0];
        #pragma unroll
        for (int w2 = 0; w2 < 4; ++w2)
            o += *(const float*)(smem + OUTP_OFF + (w2 * 64 + tid) * 4);
        out[(b << 6) + tid] = o;
    }
}

extern "C" void kernel_launch(void* const* d_in, const int* in_sizes, int n_in,
                              void* d_out, int out_size, void* d_ws, size_t ws_size,
                              hipStream_t stream) {
    const int*   q_ids  = (const int*)d_in[0];
    const int*   c_ids  = (const int*)d_in[1];
    const int*   num_qs = (const int*)d_in[2];
    // d_in[3] num_cols: unused by the reference forward
    const float* embed  = (const float*)d_in[4];
    const float* W_h    = (const float*)d_in[5];
    const float* b_h    = (const float*)d_in[6];
    const float* W_o    = (const float*)d_in[7];
    const float* b_o    = (const float*)d_in[8];
    float*       out    = (float*)d_out;
    unsigned short* whT = (unsigned short*)d_ws;   // 128*640*2 = 163840 B

    el_prep<<<320, 256, 0, stream>>>(W_h, whT);
    el_main<<<1024, 256, 0, stream>>>(q_ids, c_ids, num_qs, embed, whT,
                                      b_h, W_o, b_o, out);
}

// Round 3
// 158.590 us; speedup vs baseline: 1.0799x; 1.0799x over previous
//
#include <hip/hip_runtime.h>

// EntityLinker forward, MI355X/gfx950. One block per batch b, 256 thr (4 waves).
// R3: bf16 embed table (ws-guarded), ids->LDS preload, 16B/lane gather,
//     LDS 51.5K -> 3 blocks/CU, prod/absd in-register in P5, QHT built in P2.

typedef __attribute__((ext_vector_type(8))) short     short8;
typedef __attribute__((ext_vector_type(8))) __bf16    bf16x8;
typedef __attribute__((ext_vector_type(4))) float     f32x4;

#define SWZ(row, off) ((off) ^ (((row) & 7) << 4))

// ---- LDS layout (bytes) ----
// CH  [64][128]bf16 (256B rows, swz)          0..16K
// QH  [64][128]bf16 q_h -> att[64][64] in first 8K -> wq full   16K..32K
// QHT [128][64]bf16 (128B rows, swz)          32K..48K
// X: ids (P1) / qsum-partials+qsum / out-partials
#define CH_OFF    0
#define QH_OFF    16384
#define QHT_OFF   32768
#define X_OFF     49152
#define IDS_C     (X_OFF)            // 512 int (P1 only)
#define IDS_Q     (X_OFF + 2048)     // 64 int  (P1 only)
#define QSP_OFF   (X_OFF)            // f32[2][128] (P2..P3end)
#define QSUM_OFF  (X_OFF + 1024)     // bf16[128]   (P3end..P5)
#define OUTP_OFF  (X_OFF + 1280)     // f32[4][64]  (P5..P6)
#define LDS_SIZE  (X_OFF + 2304)     // 51456 -> 3 blocks/CU

__device__ __forceinline__ unsigned short f2bf(float x) {
    unsigned u = __builtin_bit_cast(unsigned, x);
    u += 0x7FFFu + ((u >> 16) & 1u);          // RNE
    return (unsigned short)(u >> 16);
}
__device__ __forceinline__ float bf2f(unsigned short u) {
    return __builtin_bit_cast(float, ((unsigned)u) << 16);
}
__device__ __forceinline__ float bflo(unsigned u) {
    return __builtin_bit_cast(float, u << 16);
}
__device__ __forceinline__ float bfhi(unsigned u) {
    return __builtin_bit_cast(float, u & 0xFFFF0000u);
}
__device__ __forceinline__ f32x4 mfma16(short8 a, short8 b, f32x4 c) {
    return __builtin_amdgcn_mfma_f32_16x16x32_bf16(
        __builtin_bit_cast(bf16x8, a), __builtin_bit_cast(bf16x8, b), c, 0, 0, 0);
}

// W_h [640][128] f32 -> whT [128][640] bf16 (scatter writes; tiny kernel).
__global__ __launch_bounds__(256) void el_prep(const float* __restrict__ W_h,
                                               unsigned short* __restrict__ whT) {
    int t = blockIdx.x * 256 + threadIdx.x;
    int k = t >> 7, n = t & 127;
    whT[n * 640 + k] = f2bf(W_h[t]);
}

// embed f32 [100000][128] -> bf16 table in ws.
__global__ __launch_bounds__(256) void el_conv(const float* __restrict__ e,
                                               unsigned short* __restrict__ ebf) {
    long i = ((long)blockIdx.x * 256 + threadIdx.x) * 8;
    f32x4 a = *(const f32x4*)(e + i);
    f32x4 c = *(const f32x4*)(e + i + 4);
    uint4 pk;
    pk.x = (unsigned)f2bf(a[0]) | ((unsigned)f2bf(a[1]) << 16);
    pk.y = (unsigned)f2bf(a[2]) | ((unsigned)f2bf(a[3]) << 16);
    pk.z = (unsigned)f2bf(c[0]) | ((unsigned)f2bf(c[1]) << 16);
    pk.w = (unsigned)f2bf(c[2]) | ((unsigned)f2bf(c[3]) << 16);
    *(uint4*)(ebf + i) = pk;
}

template <bool BF16E>
__global__ __launch_bounds__(256, 3) void el_main(
    const int* __restrict__ q_ids, const int* __restrict__ c_ids,
    const int* __restrict__ num_qs, const float* __restrict__ emb,
    const unsigned short* __restrict__ ebf,
    const unsigned short* __restrict__ whT, const float* __restrict__ b_h,
    const float* __restrict__ W_o, const float* __restrict__ b_o,
    float* __restrict__ out)
{
    __shared__ __align__(16) char smem[LDS_SIZE];
    const int tid = threadIdx.x;
    const int b = blockIdx.x;
    const int nq = num_qs[b] > 0 ? num_qs[b] : 1;

    // ---------------- P0: ids -> LDS ----------------
    {
        int* idc = (int*)(smem + IDS_C);
        idc[tid]       = c_ids[(b << 9) + tid];
        idc[tid + 256] = c_ids[(b << 9) + tid + 256];
        if (tid < 64) ((int*)(smem + IDS_Q))[tid] = q_ids[(b << 6) + tid];
    }
    __syncthreads();

    // ---------------- P1: gathers ----------------
    if constexpr (BF16E) {
        const int l4 = tid & 15, gg = tid >> 4;       // 16 groups of 16 lanes
        #pragma unroll 2
        for (int cc = 0; cc < 4; ++cc) {
            const int c = gg + cc * 16;
            const int* idp = (const int*)(smem + IDS_C) + c * 8;
            int id8[8];
            #pragma unroll
            for (int t = 0; t < 8; ++t) id8[t] = idp[t];
            float acc[8] = {0.f,0.f,0.f,0.f,0.f,0.f,0.f,0.f};
            int cnt = 0;
            #pragma unroll
            for (int t = 0; t < 8; ++t) {
                uint4 v = *(const uint4*)(ebf + (long)id8[t] * 128 + l4 * 8);
                cnt += (id8[t] != 0);
                acc[0] += bflo(v.x); acc[1] += bfhi(v.x);
                acc[2] += bflo(v.y); acc[3] += bfhi(v.y);
                acc[4] += bflo(v.z); acc[5] += bfhi(v.z);
                acc[6] += bflo(v.w); acc[7] += bfhi(v.w);
            }
            float inv = 1.0f / (float)(cnt > 0 ? cnt : 1);
            uint4 pk;
            pk.x = (unsigned)f2bf(acc[0]*inv) | ((unsigned)f2bf(acc[1]*inv) << 16);
            pk.y = (unsigned)f2bf(acc[2]*inv) | ((unsigned)f2bf(acc[3]*inv) << 16);
            pk.z = (unsigned)f2bf(acc[4]*inv) | ((unsigned)f2bf(acc[5]*inv) << 16);
            pk.w = (unsigned)f2bf(acc[6]*inv) | ((unsigned)f2bf(acc[7]*inv) << 16);
            *(uint4*)(smem + CH_OFF + SWZ(c, c * 256 + l4 * 16)) = pk;
        }
        #pragma unroll
        for (int qq = 0; qq < 4; ++qq) {
            const int q = gg + qq * 16;
            int id = ((const int*)(smem + IDS_Q))[q];
            uint4 v = *(const uint4*)(ebf + (long)id * 128 + l4 * 8);
            *(uint4*)(smem + QH_OFF + SWZ(q, q * 256 + l4 * 16)) = v;  // bf16 copy
        }
    } else {
        const int l = tid & 31, g = tid >> 5;         // 8 groups of 32 lanes
        #pragma unroll 2
        for (int cc = 0; cc < 8; ++cc) {
            const int c = g + cc * 8;
            const int* idp = (const int*)(smem + IDS_C) + c * 8;
            int id8[8];
            #pragma unroll
            for (int t = 0; t < 8; ++t) id8[t] = idp[t];
            f32x4 acc = {0.f, 0.f, 0.f, 0.f};
            int cnt = 0;
            #pragma unroll
            for (int t = 0; t < 8; ++t) {
                f32x4 v = *(const f32x4*)(emb + (long)id8[t] * 128 + l * 4);
                cnt += (id8[t] != 0);
                acc += v;
            }
            float inv = 1.0f / (float)(cnt > 0 ? cnt : 1);
            uint2 pk;
            pk.x = (unsigned)f2bf(acc[0]*inv) | ((unsigned)f2bf(acc[1]*inv) << 16);
            pk.y = (unsigned)f2bf(acc[2]*inv) | ((unsigned)f2bf(acc[3]*inv) << 16);
            *(uint2*)(smem + CH_OFF + SWZ(c, c * 256 + l * 8)) = pk;
        }
        #pragma unroll
        for (int qq = 0; qq < 8; ++qq) {
            const int q = g + qq * 8;
            int id = ((const int*)(smem + IDS_Q))[q];
            f32x4 v = *(const f32x4*)(emb + (long)id * 128 + l * 4);
            uint2 pk;
            pk.x = (unsigned)f2bf(v[0]) | ((unsigned)f2bf(v[1]) << 16);
            pk.y = (unsigned)f2bf(v[2]) | ((unsigned)f2bf(v[3]) << 16);
            *(uint2*)(smem + QH_OFF + SWZ(q, q * 256 + l * 8)) = pk;
        }
    }
    __syncthreads();

    // ---------------- P2: QHT build + q_summary partials (both read QH) ----
    {
        const int d = tid >> 1, qh = (tid & 1) * 32;
        unsigned v16[32];
        #pragma unroll
        for (int j = 0; j < 32; ++j) {
            int q = qh + j;
            v16[j] = *(const unsigned short*)(smem + QH_OFF + SWZ(q, q * 256 + d * 2));
        }
        #pragma unroll
        for (int i = 0; i < 4; ++i) {
            uint4 pk;
            pk.x = v16[i*8+0] | (v16[i*8+1] << 16);
            pk.y = v16[i*8+2] | (v16[i*8+3] << 16);
            pk.z = v16[i*8+4] | (v16[i*8+5] << 16);
            pk.w = v16[i*8+6] | (v16[i*8+7] << 16);
            *(uint4*)(smem + QHT_OFF + SWZ(d, d * 128 + qh * 2 + i * 16)) = pk;
        }
        const int d2 = tid & 127, h = tid >> 7;
        float s = 0.f;
        #pragma unroll
        for (int j = 0; j < 32; ++j) {
            int q = h * 32 + j;
            float v = bf2f(*(const unsigned short*)(smem + QH_OFF + SWZ(q, q * 256 + d2 * 2)));
            s += (q < nq) ? v : 0.f;
        }
        ((float*)(smem + QSP_OFF))[h * 128 + d2] = s;
    }
    __syncthreads();

    const int lane = tid & 63, w = tid >> 6;
    const int lr = lane & 15, lg = lane >> 4;

    // ---------------- P3: sim + in-reg softmax ----------------
    float attv[4][4];
    {
        short8 a[4];
        const int arow = w * 16 + lr;
        #pragma unroll
        for (int s = 0; s < 4; ++s)
            a[s] = *(const short8*)(smem + CH_OFF + SWZ(arow, arow * 256 + s * 64 + lg * 16));
        f32x4 sim[4];
        #pragma unroll
        for (int ct = 0; ct < 4; ++ct) {
            f32x4 acc = {0.f, 0.f, 0.f, 0.f};
            const int q = ct * 16 + lr;
            #pragma unroll
            for (int s = 0; s < 4; ++s) {
                short8 bf = *(const short8*)(smem + QH_OFF + SWZ(q, q * 256 + s * 64 + lg * 16));
                acc = mfma16(a[s], bf, acc);
            }
            sim[ct] = acc;
        }
        const float scale = 0.08838834764831845f;  // 1/sqrt(128)
        #pragma unroll
        for (int ct = 0; ct < 4; ++ct) {
            const int q = ct * 16 + lr;
            #pragma unroll
            for (int r = 0; r < 4; ++r)
                sim[ct][r] = (q < nq) ? sim[ct][r] * scale : -3.0e38f;
        }
        float mx[4], sm[4];
        #pragma unroll
        for (int r = 0; r < 4; ++r)
            mx[r] = fmaxf(fmaxf(sim[0][r], sim[1][r]), fmaxf(sim[2][r], sim[3][r]));
        #pragma unroll
        for (int off = 1; off <= 8; off <<= 1)
            #pragma unroll
            for (int r = 0; r < 4; ++r)
                mx[r] = fmaxf(mx[r], __shfl_xor(mx[r], off));
        #pragma unroll
        for (int ct = 0; ct < 4; ++ct)
            #pragma unroll
            for (int r = 0; r < 4; ++r)
                sim[ct][r] = __expf(sim[ct][r] - mx[r]);
        #pragma unroll
        for (int r = 0; r < 4; ++r)
            sm[r] = (sim[0][r] + sim[1][r]) + (sim[2][r] + sim[3][r]);
        #pragma unroll
        for (int off = 1; off <= 8; off <<= 1)
            #pragma unroll
            for (int r = 0; r < 4; ++r)
                sm[r] += __shfl_xor(sm[r], off);
        #pragma unroll
        for (int ct = 0; ct < 4; ++ct)
            #pragma unroll
            for (int r = 0; r < 4; ++r)
                attv[ct][r] = sim[ct][r] * (1.0f / sm[r]);
    }
    __syncthreads();   // all QH(q_h) reads done -> att may overwrite QH[0:8K]
    {
        const int cbase = w * 16 + lg * 4;
        #pragma unroll
        for (int ct = 0; ct < 4; ++ct)
            #pragma unroll
            for (int r = 0; r < 4; ++r) {
                int c = cbase + r, q = ct * 16 + lr;
                *(unsigned short*)(smem + QH_OFF + SWZ(c, c * 128 + q * 2)) =
                    f2bf(attv[ct][r]);
            }
        if (tid < 128) {
            const float* qsp = (const float*)(smem + QSP_OFF);
            float s = (qsp[tid] + qsp[128 + tid]) / (float)nq;
            *(unsigned short*)(smem + QSUM_OFF + tid * 2) = f2bf(s);
        }
    }
    __syncthreads();

    // ---------------- P4: weighted_q = att @ q_h ----------------
    f32x4 wqa[8];
    {
        short8 pa[2];
        const int prow = w * 16 + lr;
        #pragma unroll
        for (int s = 0; s < 2; ++s)
            pa[s] = *(const short8*)(smem + QH_OFF + SWZ(prow, prow * 128 + s * 64 + lg * 16));
        #pragma unroll
        for (int ct = 0; ct < 8; ++ct) {
            f32x4 acc = {0.f, 0.f, 0.f, 0.f};
            const int dcol = ct * 16 + lr;
            #pragma unroll
            for (int s = 0; s < 2; ++s) {
                short8 bf = *(const short8*)(smem + QHT_OFF + SWZ(dcol, dcol * 128 + s * 64 + lg * 16));
                acc = mfma16(pa[s], bf, acc);
            }
            wqa[ct] = acc;
        }
    }
    __syncthreads();   // att reads done -> wq may overwrite full QH
    {
        const int cbase = w * 16 + lg * 4;
        #pragma unroll
        for (int ct = 0; ct < 8; ++ct)
            #pragma unroll
            for (int r = 0; r < 4; ++r) {
                int c = cbase + r, d = ct * 16 + lr;
                *(unsigned short*)(smem + QH_OFF + SWZ(c, c * 256 + d * 2)) = f2bf(wqa[ct][r]);
            }
    }
    __syncthreads();

    // ---------------- P5: h = tanh(feats @ W_h + b_h); out = h @ W_o -------
    {
        f32x4 acc[4][2];
        #pragma unroll
        for (int rt = 0; rt < 4; ++rt) {
            acc[rt][0] = (f32x4){0.f, 0.f, 0.f, 0.f};
            acc[rt][1] = (f32x4){0.f, 0.f, 0.f, 0.f};
        }
        const int n0 = w * 32 + lr, n1 = n0 + 16;

        for (int sk = 0; sk < 4; ++sk) {
            short8 B0[5], B1[5];
            #pragma unroll
            for (int p = 0; p < 5; ++p) {
                B0[p] = *(const short8*)(whT + n0 * 640 + p * 128 + sk * 32 + lg * 8);
                B1[p] = *(const short8*)(whT + n1 * 640 + p * 128 + sk * 32 + lg * 8);
            }
            short8 qsf = *(const short8*)(smem + QSUM_OFF + sk * 64 + lg * 16);
            #pragma unroll
            for (int rt = 0; rt < 4; ++rt) {
                const int row = rt * 16 + lr;
                short8 chf = *(const short8*)(smem + CH_OFF + SWZ(row, row * 256 + sk * 64 + lg * 16));
                short8 wqf = *(const short8*)(smem + QH_OFF + SWZ(row, row * 256 + sk * 64 + lg * 16));
                short8 prf, adf;
                #pragma unroll
                for (int e = 0; e < 8; ++e) {
                    float cv = bf2f((unsigned short)chf[e]);
                    float wv = bf2f((unsigned short)wqf[e]);
                    prf[e] = (short)f2bf(cv * wv);
                    adf[e] = (short)f2bf(fabsf(cv - wv));
                }
                acc[rt][0] = mfma16(qsf, B0[0], acc[rt][0]);
                acc[rt][1] = mfma16(qsf, B1[0], acc[rt][1]);
                acc[rt][0] = mfma16(chf, B0[1], acc[rt][0]);
                acc[rt][1] = mfma16(chf, B1[1], acc[rt][1]);
                acc[rt][0] = mfma16(wqf, B0[2], acc[rt][0]);
                acc[rt][1] = mfma16(wqf, B1[2], acc[rt][1]);
                acc[rt][0] = mfma16(prf, B0[3], acc[rt][0]);
                acc[rt][1] = mfma16(prf, B1[3], acc[rt][1]);
                acc[rt][0] = mfma16(adf, B0[4], acc[rt][0]);
                acc[rt][1] = mfma16(adf, B1[4], acc[rt][1]);
            }
        }

        float bh0 = b_h[n0], bh1 = b_h[n1];
        float wo0 = W_o[n0], wo1 = W_o[n1];
        #pragma unroll
        for (int rt = 0; rt < 4; ++rt)
            #pragma unroll
            for (int r = 0; r < 4; ++r) {
                float x0 = acc[rt][0][r] + bh0;
                float x1 = acc[rt][1][r] + bh1;
                float t0 = 1.0f - 2.0f / (__expf(2.0f * x0) + 1.0f);
                float t1 = 1.0f - 2.0f / (__expf(2.0f * x1) + 1.0f);
                float po = t0 * wo0 + t1 * wo1;
                #pragma unroll
                for (int off = 1; off <= 8; off <<= 1)
                    po += __shfl_xor(po, off);
                if (lr == 0)
                    *(float*)(smem + OUTP_OFF + (w * 64 + rt * 16 + lg * 4 + r) * 4) = po;
            }
    }
    __syncthreads();

    // ---------------- P6: combine wave partials ----------------
    if (tid < 64) {
        float o = b_o[0];
        #pragma unroll
        for (int w2 = 0; w2 < 4; ++w2)
            o += *(const float*)(smem + OUTP_OFF + (w2 * 64 + tid) * 4);
        out[(b << 6) + tid] = o;
    }
}

extern "C" void kernel_launch(void* const* d_in, const int* in_sizes, int n_in,
                              void* d_out, int out_size, void* d_ws, size_t ws_size,
                              hipStream_t stream) {
    const int*   q_ids  = (const int*)d_in[0];
    const int*   c_ids  = (const int*)d_in[1];
    const int*   num_qs = (const int*)d_in[2];
    // d_in[3] num_cols: unused by the reference forward
    const float* embed  = (const float*)d_in[4];
    const float* W_h    = (const float*)d_in[5];
    const float* b_h    = (const float*)d_in[6];
    const float* W_o    = (const float*)d_in[7];
    const float* b_o    = (const float*)d_in[8];
    float*       out    = (float*)d_out;

    unsigned short* whT = (unsigned short*)d_ws;            // 163840 B
    unsigned short* ebf = (unsigned short*)d_ws + 81920;    // 25.6 MB

    el_prep<<<320, 256, 0, stream>>>(W_h, whT);

    const bool bf16e = ws_size >= (size_t)(163840 + 100000 * 128 * 2);
    if (bf16e) {
        el_conv<<<6250, 256, 0, stream>>>(embed, ebf);
        el_main<true><<<1024, 256, 0, stream>>>(q_ids, c_ids, num_qs, embed, ebf,
                                                whT, b_h, W_o, b_o, out);
    } else {
        el_main<false><<<1024, 256, 0, stream>>>(q_ids, c_ids, num_qs, embed, ebf,
                                                 whT, b_h, W_o, b_o, out);
    }
}